// Round 5
// baseline (1031.182 us; speedup 1.0000x reference)
//
#include <hip/hip_runtime.h>

typedef unsigned int  u32;
typedef unsigned short u16;

#define B_SESS 4096
#define NPS    40          // nodes / session
#define SPS    50          // seq tokens / session
#define EPS    60          // edges / session
#define DIM    512
#define HID    64
#define NNODES (B_SESS * NPS)

// ---------- bf16 helpers (RNE) ----------
__device__ __forceinline__ float bf2f(u32 b) { return __uint_as_float(b << 16); }
__device__ __forceinline__ u16  f2bf(float f) {
    u32 u = __float_as_uint(f);
    return (u16)((u + 0x7fffu + ((u >> 16) & 1u)) >> 16);
}
__device__ __forceinline__ u32 pack2(float a, float b) {
    return (u32)f2bf(a) | ((u32)f2bf(b) << 16);
}

typedef __bf16 bf16x8 __attribute__((ext_vector_type(8)));
typedef float  f32x4  __attribute__((ext_vector_type(4)));

typedef const __attribute__((address_space(1))) u32 gu32;
typedef       __attribute__((address_space(3))) u32 lu32;
#define GLOAD_LDS16(gp, lp) \
    __builtin_amdgcn_global_load_lds((gu32*)(gp), (lu32*)(lp), 16, 0, 0)

// ---------- transpose + fp32->bf16 convert: dst[c*R + r] = bf16(src[r*C + c]) ----
extern "C" __global__ void k_convT(const float* __restrict__ src,
                                   u16* __restrict__ dst, int R, int C) {
    int i = blockIdx.x * 256 + threadIdx.x;
    if (i < R * C) {
        int r = i / C, c = i % C;
        dst[c * R + r] = f2bf(src[i]);
    }
}

// ---------- GEMM1: Y[N,512] = bf16(hid fp32) @ WgT   (no bias; bias in k_prop) ----
// A is fp32: reg-staged (float4 load -> cvt -> ds_write) with next-tile prefetch;
// B staged via global_load_lds. 1D grid, XCD-chunked swizzle.
#define GEMM_NBLK ((NNODES / 128) * (DIM / 128))   // 5120, % 8 == 0
extern "C" __global__ __launch_bounds__(256)
void k_gemm(const float* __restrict__ A, const u16* __restrict__ BT,
            u16* __restrict__ C) {
    __shared__ __align__(16) u16 As[128 * 32];
    __shared__ __align__(16) u16 Bs[128 * 32];
    int tid  = threadIdx.x, lane = tid & 63, w = tid >> 6;
    int id   = blockIdx.x;
    int swz  = (id & 7) * (GEMM_NBLK / 8) + (id >> 3);
    int m0   = (swz >> 2) * 128, n0 = (swz & 3) * 128;
    int wm   = (w >> 1) * 64,    wn = (w & 1) * 64;
    int fr   = lane & 15,        kq = (lane >> 4) * 8;
    int lr   = lane >> 2;              // B staging: row within 16-row chunk
    int lk   = (lane & 3) * 8;         // B staging: k offset (u16 units)
    int ar   = tid >> 3;               // A staging: row (0..127) -- 4 passes stride 32
    int ac   = (tid & 7) * 4;          // A staging: col (fp32 units)
    f32x4 acc[4][4] = {};
    float4 pa0, pa1, pa2, pa3;

    // prefetch A tile kt=0 (rows ar, ar+32, ar+64, ar+96; cols ac..ac+4)
    {
        const float* ap = A + (size_t)(m0 + ar) * DIM + ac;
        pa0 = *(const float4*)(ap);
        pa1 = *(const float4*)(ap + 32 * DIM);
        pa2 = *(const float4*)(ap + 64 * DIM);
        pa3 = *(const float4*)(ap + 96 * DIM);
    }

    for (int kt = 0; kt < 16; kt++) {
        __syncthreads();
        // A: regs -> LDS (bf16)
        *(uint2*)&As[(ar +  0) * 32 + ac] = make_uint2(pack2(pa0.x, pa0.y), pack2(pa0.z, pa0.w));
        *(uint2*)&As[(ar + 32) * 32 + ac] = make_uint2(pack2(pa1.x, pa1.y), pack2(pa1.z, pa1.w));
        *(uint2*)&As[(ar + 64) * 32 + ac] = make_uint2(pack2(pa2.x, pa2.y), pack2(pa2.z, pa2.w));
        *(uint2*)&As[(ar + 96) * 32 + ac] = make_uint2(pack2(pa3.x, pa3.y), pack2(pa3.z, pa3.w));
        // B: async direct to LDS
#pragma unroll
        for (int q = 0; q < 2; q++) {
            int r0 = (w * 2 + q) * 16;
            GLOAD_LDS16(BT + (size_t)(n0 + r0 + lr) * DIM + kt * 32 + lk, Bs + r0 * 32);
        }
        // prefetch A tile kt+1 (latency hides under MFMA)
        if (kt < 15) {
            const float* ap = A + (size_t)(m0 + ar) * DIM + (kt + 1) * 32 + ac;
            pa0 = *(const float4*)(ap);
            pa1 = *(const float4*)(ap + 32 * DIM);
            pa2 = *(const float4*)(ap + 64 * DIM);
            pa3 = *(const float4*)(ap + 96 * DIM);
        }
        __syncthreads();
        bf16x8 av[4], bv[4];
#pragma unroll
        for (int f = 0; f < 4; f++)
            av[f] = *(const bf16x8*)&As[(wm + f * 16 + fr) * 32 + kq];
#pragma unroll
        for (int f = 0; f < 4; f++)
            bv[f] = *(const bf16x8*)&Bs[(wn + f * 16 + fr) * 32 + kq];
#pragma unroll
        for (int fm = 0; fm < 4; fm++)
#pragma unroll
            for (int fn = 0; fn < 4; fn++)
                acc[fm][fn] = __builtin_amdgcn_mfma_f32_16x16x32_bf16(
                    av[fm], bv[fn], acc[fm][fn], 0, 0, 0);
    }

#pragma unroll
    for (int fm = 0; fm < 4; fm++) {
        int mb = m0 + wm + fm * 16 + (lane >> 4) * 4;
#pragma unroll
        for (int fn = 0; fn < 4; fn++) {
            int col = n0 + wn + fn * 16 + fr;
#pragma unroll
            for (int r = 0; r < 4; r++)
                C[(size_t)(mb + r) * DIM + col] = f2bf(acc[fm][fn][r]);
        }
    }
}

// ---------- SGConv: xg = P^2 @ Y + bg  (Y bf16, L3-resident) ----------
// one block per session; builds dense P, squares it, compacts to a dst-sorted
// entry list in LDS, then gathers. Thread owns 2 bf16 cols (u32 loads).
extern "C" __global__ __launch_bounds__(256)
void k_prop(const u16* __restrict__ Y, const int* __restrict__ eidx, int Etot,
            const float* __restrict__ bg, u16* __restrict__ xg) {
    __shared__ float P [NPS][NPS];           // 6.4 KB
    __shared__ float P2[NPS][NPS];           // 6.4 KB
    __shared__ uint2 em[NPS * NPS];          // 12.8 KB (worst-case nnz)
    __shared__ int   degc[NPS];
    __shared__ float dinv[NPS];
    __shared__ int   se[EPS], de[EPS];
    __shared__ int   rc[NPS], offs[NPS + 1];

    int tid = threadIdx.x;
    int b   = (blockIdx.x & 7) * (B_SESS / 8) + (blockIdx.x >> 3);
    int nb  = b * NPS;

    if (tid < EPS) {
        se[tid] = eidx[b * EPS + tid] - nb;
        de[tid] = eidx[Etot + b * EPS + tid] - nb;
    }
    if (tid < NPS) degc[tid] = 1;            // self loop
    for (int i = tid; i < NPS * NPS; i += 256) (&P[0][0])[i] = 0.f;
    __syncthreads();
    if (tid < EPS) atomicAdd(&degc[de[tid]], 1);
    __syncthreads();
    if (tid < NPS) dinv[tid] = rsqrtf((float)degc[tid]);
    __syncthreads();
    if (tid < NPS) atomicAdd(&P[tid][tid], dinv[tid] * dinv[tid]);
    if (tid < EPS) {
        int s = se[tid], d = de[tid];
        atomicAdd(&P[d][s], dinv[s] * dinv[d]);
    }
    __syncthreads();

    // P2 = P @ P  (thread computes a 1x4 chunk)
    for (int i = tid; i < NPS * (NPS / 4); i += 256) {
        int d = i / (NPS / 4), q = (i % (NPS / 4)) * 4;
        float4 acc = make_float4(0.f, 0.f, 0.f, 0.f);
#pragma unroll 8
        for (int k = 0; k < NPS; k++) {
            float  pk = P[d][k];
            float4 pv = *(const float4*)&P[k][q];
            acc.x += pk * pv.x; acc.y += pk * pv.y;
            acc.z += pk * pv.z; acc.w += pk * pv.w;
        }
        *(float4*)&P2[d][q] = acc;
    }
    __syncthreads();

    if (tid < NPS) {                         // row nnz (all entries >= 0)
        int c = 0;
        for (int s = 0; s < NPS; s++) c += (P2[tid][s] > 0.f);
        rc[tid] = c;
    }
    __syncthreads();
    if (tid == 0) {
        int s = 0;
        for (int i = 0; i < NPS; i++) { offs[i] = s; s += rc[i]; }
        offs[NPS] = s;
    }
    __syncthreads();
    if (tid < NPS) {
        int d = tid, o = offs[d], last = offs[d] + rc[d] - 1;
        for (int s = 0; s < NPS; s++) {
            float v = P2[d][s];
            if (v > 0.f) {
                u32 x = (u32)(d << 8) | (u32)s | ((o == last) ? 0x10000u : 0u);
                em[o] = make_uint2(x, __float_as_uint(v));
                o++;
            }
        }
    }
    __syncthreads();

    int n = offs[NPS];
    const u32* yr = (const u32*)(Y + (size_t)nb * DIM) + tid;   // cols 2t,2t+1
    u32*       xo = (u32*)(xg + (size_t)nb * DIM) + tid;
    float2 bgv = *(const float2*)&bg[2 * tid];

    float a0 = 0.f, a1 = 0.f;
#pragma unroll 8
    for (int p = 0; p < n; p++) {
        uint2 e = em[p];
        float nm = __uint_as_float(e.y);
        u32 v = yr[(size_t)(e.x & 0xffu) * (DIM / 2)];
        a0 += nm * bf2f(v & 0xffffu);
        a1 += nm * bf2f(v >> 16);
        if (e.x & 0x10000u) {
            int d = (e.x >> 8) & 0xffu;
            xo[(size_t)d * (DIM / 2)] = pack2(a0 + bgv.x, a1 + bgv.y);
            a0 = a1 = 0.f;
        }
    }
}

// ---------- A2 = xg @ W2  [N,64] bf16, dense streaming MFMA, no LDS ----------
extern "C" __global__ __launch_bounds__(256)
void k_a2(const u16* __restrict__ xg, const u16* __restrict__ W2T,
          u16* __restrict__ A2) {
    int tid = threadIdx.x, lane = tid & 63, w = tid >> 6;
    int m0  = blockIdx.x * 256 + w * 64;
    int fr  = lane & 15, kq = (lane >> 4) * 8;
    f32x4 acc[4][4] = {};

    for (int kt = 0; kt < 16; kt++) {
        bf16x8 bv[4];
#pragma unroll
        for (int fn = 0; fn < 4; fn++)
            bv[fn] = *(const bf16x8*)&W2T[(size_t)(fn * 16 + fr) * DIM + kt * 32 + kq];
#pragma unroll
        for (int fm = 0; fm < 4; fm++) {
            bf16x8 av = *(const bf16x8*)&xg[(size_t)(m0 + fm * 16 + fr) * DIM + kt * 32 + kq];
#pragma unroll
            for (int fn = 0; fn < 4; fn++)
                acc[fm][fn] = __builtin_amdgcn_mfma_f32_16x16x32_bf16(
                    av, bv[fn], acc[fm][fn], 0, 0, 0);
        }
    }
#pragma unroll
    for (int fm = 0; fm < 4; fm++) {
        int mb = m0 + fm * 16 + (lane >> 4) * 4;
#pragma unroll
        for (int fn = 0; fn < 4; fn++) {
            int col = fn * 16 + fr;
#pragma unroll
            for (int r = 0; r < 4; r++)
                A2[(size_t)(mb + r) * HID + col] = f2bf(acc[fm][fn][r]);
        }
    }
}

// ---------- q1[b] = v_n[b] @ W1 + b1 + b2  [B,64] fp32 ----------
extern "C" __global__ __launch_bounds__(256)
void k_q1(const u16* __restrict__ xg, const u16* __restrict__ W1T,
          const float* __restrict__ b1, const float* __restrict__ b2,
          const int* __restrict__ sidx, float* __restrict__ q1g) {
    __shared__ __align__(16) u16 vs[64 * 520];
    int tid = threadIdx.x, lane = tid & 63, w = tid >> 6;
    int b0  = blockIdx.x * 64;

    for (int t = w; t < 64; t += 4) {
        int brow = b0 + t;
        size_t node = (size_t)brow * NPS + sidx[brow * SPS + SPS - 1];
        GLOAD_LDS16(xg + node * DIM + lane * 8, vs + t * 520);
    }
    __syncthreads();

    int fr = lane & 15, kq = (lane >> 4) * 8;
    f32x4 acc[4] = {};
    for (int kt = 0; kt < 16; kt++) {
        bf16x8 av = *(const bf16x8*)&vs[(w * 16 + fr) * 520 + kt * 32 + kq];
#pragma unroll
        for (int fn = 0; fn < 4; fn++) {
            bf16x8 bv = *(const bf16x8*)&W1T[(size_t)(fn * 16 + fr) * DIM + kt * 32 + kq];
            acc[fn] = __builtin_amdgcn_mfma_f32_16x16x32_bf16(av, bv, acc[fn], 0, 0, 0);
        }
    }
#pragma unroll
    for (int fn = 0; fn < 4; fn++) {
        int col = fn * 16 + fr;
        float bb = b1[col] + b2[col];
#pragma unroll
        for (int r = 0; r < 4; r++) {
            int brow = b0 + w * 16 + (lane >> 4) * 4 + r;
            q1g[(size_t)brow * HID + col] = acc[fn][r] + bb;
        }
    }
}

// ---------- lite attention pooling, one block per session (no big LDS) ----------
extern "C" __global__ __launch_bounds__(256)
void k_attn(const u16* __restrict__ xg, const u16* __restrict__ A2,
            const float* __restrict__ q1g, const float* __restrict__ Wq,
            const float* __restrict__ bq, const u16* __restrict__ W3T,
            const float* __restrict__ b3, const int* __restrict__ sidx,
            float* __restrict__ out) {
    __shared__ __align__(16) u16 a2s[SPS * HID];   // 6.4 KB
    __shared__ float q1s[64], wqs[64], alphas[64], sgs[512], part[256];
    __shared__ int   nodes[64];
    int tid = threadIdx.x, lane = tid & 63, w = tid >> 6;
    int b = blockIdx.x, sb = b * SPS;
    int nb = b * NPS;

    if (tid < SPS) nodes[tid] = nb + sidx[sb + tid];
    if (tid < 64) { q1s[tid] = q1g[(size_t)b * HID + tid]; wqs[tid] = Wq[tid]; }
    __syncthreads();

    // stage a2 token rows: 50 x 64 bf16 = 1600 u32
    {
        const u32* A2u = (const u32*)A2;
        u32* a2u = (u32*)a2s;
        for (int i = tid; i < SPS * (HID / 2); i += 256) {
            int r = i >> 5, c = i & 31;
            a2u[i] = A2u[(size_t)nodes[r] * (HID / 2) + c];
        }
    }
    __syncthreads();

    // alphas: wave w handles tokens w, w+4, ...
    float bqf = bq[0];
    for (int t = w; t < SPS; t += 4) {
        float x = bf2f(a2s[t * HID + lane]) + q1s[lane];
        float sg = 1.0f / (1.0f + __expf(-x));
        float s = sg * wqs[lane];
        s += __shfl_xor(s, 1);  s += __shfl_xor(s, 2);  s += __shfl_xor(s, 4);
        s += __shfl_xor(s, 8);  s += __shfl_xor(s, 16); s += __shfl_xor(s, 32);
        if (lane == 0) alphas[t] = s + bqf;
    }
    __syncthreads();

    // s_g: thread owns u32 column tid (2 bf16 cols); gather rows from xg (L3-hot)
    {
        const u32* xgu = (const u32*)xg;
        float a0 = 0.f, a1 = 0.f;
#pragma unroll 10
        for (int t = 0; t < SPS; t++) {
            float al = alphas[t];
            u32 xv = xgu[(size_t)nodes[t] * (DIM / 2) + tid];
            a0 += al * bf2f(xv & 0xffffu);
            a1 += al * bf2f(xv >> 16);
        }
        sgs[2 * tid] = a0; sgs[2 * tid + 1] = a1;
    }
    __syncthreads();

    // h_s = [v_n, s_g] @ W3 + b3  (W3T bf16 [64][1024]); wave w covers k 256w..+256
    {
        float s = 0.f;
        const u16* wp = W3T + (size_t)lane * 1024 + 256 * w;
        if (w < 2) {
            const u16* vp = xg + (size_t)nodes[SPS - 1] * DIM + 256 * w;
            for (int kk = 0; kk < 256; kk += 8) {
                uint4 vv = *(const uint4*)(vp + kk);
                uint4 ww = *(const uint4*)(wp + kk);
                s += bf2f(vv.x & 0xffffu) * bf2f(ww.x & 0xffffu)
                   + bf2f(vv.x >> 16)     * bf2f(ww.x >> 16)
                   + bf2f(vv.y & 0xffffu) * bf2f(ww.y & 0xffffu)
                   + bf2f(vv.y >> 16)     * bf2f(ww.y >> 16)
                   + bf2f(vv.z & 0xffffu) * bf2f(ww.z & 0xffffu)
                   + bf2f(vv.z >> 16)     * bf2f(ww.z >> 16)
                   + bf2f(vv.w & 0xffffu) * bf2f(ww.w & 0xffffu)
                   + bf2f(vv.w >> 16)     * bf2f(ww.w >> 16);
            }
        } else {
            const float* sp = sgs + 256 * (w - 2);
            for (int kk = 0; kk < 256; kk += 8) {
                uint4 ww = *(const uint4*)(wp + kk);
                s += sp[kk + 0] * bf2f(ww.x & 0xffffu) + sp[kk + 1] * bf2f(ww.x >> 16)
                   + sp[kk + 2] * bf2f(ww.y & 0xffffu) + sp[kk + 3] * bf2f(ww.y >> 16)
                   + sp[kk + 4] * bf2f(ww.z & 0xffffu) + sp[kk + 5] * bf2f(ww.z >> 16)
                   + sp[kk + 6] * bf2f(ww.w & 0xffffu) + sp[kk + 7] * bf2f(ww.w >> 16);
            }
        }
        part[w * 64 + lane] = s;
    }
    __syncthreads();
    if (tid < 64) {
        out[b * HID + tid] = part[tid] + part[64 + tid] + part[128 + tid]
                           + part[192 + tid] + b3[tid];
    }
}

extern "C" void kernel_launch(void* const* d_in, const int* in_sizes, int n_in,
                              void* d_out, int out_size, void* d_ws, size_t ws_size,
                              hipStream_t stream) {
    const float* hidden = (const float*)d_in[0];
    const float* Wg     = (const float*)d_in[1];
    const float* bg     = (const float*)d_in[2];
    const float* W1     = (const float*)d_in[3];
    const float* b1     = (const float*)d_in[4];
    const float* W2     = (const float*)d_in[5];
    const float* b2     = (const float*)d_in[6];
    const float* Wq     = (const float*)d_in[7];
    const float* bq     = (const float*)d_in[8];
    const float* W3     = (const float*)d_in[9];
    const float* b3     = (const float*)d_in[10];
    const int*   eidx   = (const int*)d_in[11];
    const int*   sidx   = (const int*)d_in[13];
    int Etot = in_sizes[11] / 2;

    char* ws = (char*)d_ws;
    // region A [0,160MB): xg (written by k_prop, read by a2/q1/attn)
    u16* xg  = (u16*)ws;
    // region B [160,320MB): Y (k_gemm -> k_prop), then A2/q1g after Y is dead
    u16* Y   = (u16*)(ws + (size_t)NNODES * DIM * 2);
    u16* WgT = (u16*)(ws + (size_t)NNODES * DIM * 4);      // 512x512 bf16
    u16* W2T = WgT + DIM * DIM;                            // 64x512  bf16
    u16* W1T = W2T + DIM * HID;                            // 64x512  bf16
    u16* W3T = W1T + DIM * HID;                            // 64x1024 bf16
    u16*   A2  = Y;                                        // N*64 bf16 (20 MB)
    float* q1g = (float*)((char*)Y + (size_t)NNODES * HID * 2);  // B*64 fp32

    k_convT<<<dim3((DIM * DIM + 255) / 256), 256, 0, stream>>>(Wg, WgT, DIM, DIM);
    k_convT<<<dim3((DIM * HID + 255) / 256), 256, 0, stream>>>(W2, W2T, DIM, HID);
    k_convT<<<dim3((DIM * HID + 255) / 256), 256, 0, stream>>>(W1, W1T, DIM, HID);
    k_convT<<<dim3((2 * DIM * HID + 255) / 256), 256, 0, stream>>>(W3, W3T, 2 * DIM, HID);
    k_gemm<<<dim3(GEMM_NBLK), 256, 0, stream>>>(hidden, WgT, Y);
    k_prop<<<dim3(B_SESS), 256, 0, stream>>>(Y, eidx, Etot, bg, xg);
    k_a2<<<dim3(NNODES / 256), 256, 0, stream>>>(xg, W2T, A2);
    k_q1<<<dim3(B_SESS / 64), 256, 0, stream>>>(xg, W1T, b1, b2, sidx, q1g);
    k_attn<<<dim3(B_SESS), 256, 0, stream>>>(xg, A2, q1g, Wq, bq, W3T, b3,
                                             sidx, (float*)d_out);
}

// Round 6
// 931.440 us; speedup vs baseline: 1.1071x; 1.1071x over previous
//
#include <hip/hip_runtime.h>

typedef unsigned int  u32;
typedef unsigned short u16;

#define B_SESS 4096
#define NPS    40          // nodes / session
#define SPS    50          // seq tokens / session
#define EPS    60          // edges / session
#define DIM    512
#define HID    64
#define NNODES (B_SESS * NPS)

// ---------- bf16 helpers (RNE) ----------
__device__ __forceinline__ float bf2f(u32 b) { return __uint_as_float(b << 16); }
__device__ __forceinline__ u16  f2bf(float f) {
    u32 u = __float_as_uint(f);
    return (u16)((u + 0x7fffu + ((u >> 16) & 1u)) >> 16);
}
__device__ __forceinline__ u32 pack2(float a, float b) {
    return (u32)f2bf(a) | ((u32)f2bf(b) << 16);
}

typedef __bf16 bf16x8 __attribute__((ext_vector_type(8)));
typedef float  f32x4  __attribute__((ext_vector_type(4)));

typedef const __attribute__((address_space(1))) u32 gu32;
typedef       __attribute__((address_space(3))) u32 lu32;
#define GLOAD_LDS16(gp, lp) \
    __builtin_amdgcn_global_load_lds((gu32*)(gp), (lu32*)(lp), 16, 0, 0)

// ---------- transpose + fp32->bf16 convert: dst[c*R + r] = bf16(src[r*C + c]) ----
extern "C" __global__ void k_convT(const float* __restrict__ src,
                                   u16* __restrict__ dst, int R, int C) {
    int i = blockIdx.x * 256 + threadIdx.x;
    if (i < R * C) {
        int r = i / C, c = i % C;
        dst[c * R + r] = f2bf(src[i]);
    }
}

// ---------- GEMM1: Y[N,512] = bf16(hid fp32) @ WgT   (no bias; bias in k_prop) ----
// A is fp32: reg-staged (float4 load -> cvt -> ds_write) with next-tile prefetch;
// B staged via global_load_lds. 1D grid, XCD-chunked swizzle.
#define GEMM_NBLK ((NNODES / 128) * (DIM / 128))   // 5120, % 8 == 0
extern "C" __global__ __launch_bounds__(256)
void k_gemm(const float* __restrict__ A, const u16* __restrict__ BT,
            u16* __restrict__ C) {
    __shared__ __align__(16) u16 As[128 * 32];
    __shared__ __align__(16) u16 Bs[128 * 32];
    int tid  = threadIdx.x, lane = tid & 63, w = tid >> 6;
    int id   = blockIdx.x;
    int swz  = (id & 7) * (GEMM_NBLK / 8) + (id >> 3);
    int m0   = (swz >> 2) * 128, n0 = (swz & 3) * 128;
    int wm   = (w >> 1) * 64,    wn = (w & 1) * 64;
    int fr   = lane & 15,        kq = (lane >> 4) * 8;
    int lr   = lane >> 2;              // B staging: row within 16-row chunk
    int lk   = (lane & 3) * 8;         // B staging: k offset (u16 units)
    int ar   = tid >> 3;               // A staging: row (0..127) -- 4 passes stride 32
    int ac   = (tid & 7) * 4;          // A staging: col (fp32 units)
    f32x4 acc[4][4] = {};
    float4 pa0, pa1, pa2, pa3;

    // prefetch A tile kt=0 (rows ar, ar+32, ar+64, ar+96; cols ac..ac+4)
    {
        const float* ap = A + (size_t)(m0 + ar) * DIM + ac;
        pa0 = *(const float4*)(ap);
        pa1 = *(const float4*)(ap + 32 * DIM);
        pa2 = *(const float4*)(ap + 64 * DIM);
        pa3 = *(const float4*)(ap + 96 * DIM);
    }

    for (int kt = 0; kt < 16; kt++) {
        __syncthreads();
        // A: regs -> LDS (bf16)
        *(uint2*)&As[(ar +  0) * 32 + ac] = make_uint2(pack2(pa0.x, pa0.y), pack2(pa0.z, pa0.w));
        *(uint2*)&As[(ar + 32) * 32 + ac] = make_uint2(pack2(pa1.x, pa1.y), pack2(pa1.z, pa1.w));
        *(uint2*)&As[(ar + 64) * 32 + ac] = make_uint2(pack2(pa2.x, pa2.y), pack2(pa2.z, pa2.w));
        *(uint2*)&As[(ar + 96) * 32 + ac] = make_uint2(pack2(pa3.x, pa3.y), pack2(pa3.z, pa3.w));
        // B: async direct to LDS
#pragma unroll
        for (int q = 0; q < 2; q++) {
            int r0 = (w * 2 + q) * 16;
            GLOAD_LDS16(BT + (size_t)(n0 + r0 + lr) * DIM + kt * 32 + lk, Bs + r0 * 32);
        }
        // prefetch A tile kt+1 (latency hides under MFMA)
        if (kt < 15) {
            const float* ap = A + (size_t)(m0 + ar) * DIM + (kt + 1) * 32 + ac;
            pa0 = *(const float4*)(ap);
            pa1 = *(const float4*)(ap + 32 * DIM);
            pa2 = *(const float4*)(ap + 64 * DIM);
            pa3 = *(const float4*)(ap + 96 * DIM);
        }
        __syncthreads();
        bf16x8 av[4], bv[4];
#pragma unroll
        for (int f = 0; f < 4; f++)
            av[f] = *(const bf16x8*)&As[(wm + f * 16 + fr) * 32 + kq];
#pragma unroll
        for (int f = 0; f < 4; f++)
            bv[f] = *(const bf16x8*)&Bs[(wn + f * 16 + fr) * 32 + kq];
#pragma unroll
        for (int fm = 0; fm < 4; fm++)
#pragma unroll
            for (int fn = 0; fn < 4; fn++)
                acc[fm][fn] = __builtin_amdgcn_mfma_f32_16x16x32_bf16(
                    av[fm], bv[fn], acc[fm][fn], 0, 0, 0);
    }

#pragma unroll
    for (int fm = 0; fm < 4; fm++) {
        int mb = m0 + wm + fm * 16 + (lane >> 4) * 4;
#pragma unroll
        for (int fn = 0; fn < 4; fn++) {
            int col = n0 + wn + fn * 16 + fr;
#pragma unroll
            for (int r = 0; r < 4; r++)
                C[(size_t)(mb + r) * DIM + col] = f2bf(acc[fm][fn][r]);
        }
    }
}

// ---------- SGConv: xg = P^2 @ Y + bg  (dense, branch-free) ----------
// one block per session; builds dense P, squares it in LDS, then each thread
// (owning 2 bf16 cols) preloads all 40 Y-row values upfront (max MLP), and
// computes 40 output rows with float4 LDS broadcasts + independent FMAs.
extern "C" __global__ __launch_bounds__(256)
void k_prop(const u16* __restrict__ Y, const int* __restrict__ eidx, int Etot,
            const float* __restrict__ bg, u16* __restrict__ xg) {
    __shared__ float P [NPS][NPS];           // 6.4 KB
    __shared__ float P2[NPS][NPS];           // 6.4 KB
    __shared__ int   degc[NPS];
    __shared__ float dinv[NPS];
    __shared__ int   se[EPS], de[EPS];

    int tid = threadIdx.x;
    int b   = (blockIdx.x & 7) * (B_SESS / 8) + (blockIdx.x >> 3);
    int nb  = b * NPS;

    if (tid < EPS) {
        se[tid] = eidx[b * EPS + tid] - nb;
        de[tid] = eidx[Etot + b * EPS + tid] - nb;
    }
    if (tid < NPS) degc[tid] = 1;            // self loop
    for (int i = tid; i < NPS * NPS; i += 256) (&P[0][0])[i] = 0.f;
    __syncthreads();
    if (tid < EPS) atomicAdd(&degc[de[tid]], 1);
    __syncthreads();
    if (tid < NPS) dinv[tid] = rsqrtf((float)degc[tid]);
    __syncthreads();
    if (tid < NPS) atomicAdd(&P[tid][tid], dinv[tid] * dinv[tid]);
    if (tid < EPS) {
        int s = se[tid], d = de[tid];
        atomicAdd(&P[d][s], dinv[s] * dinv[d]);
    }
    __syncthreads();

    // P2 = P @ P  (thread computes a 1x4 chunk)
    for (int i = tid; i < NPS * (NPS / 4); i += 256) {
        int d = i / (NPS / 4), q = (i % (NPS / 4)) * 4;
        float4 acc = make_float4(0.f, 0.f, 0.f, 0.f);
#pragma unroll 8
        for (int k = 0; k < NPS; k++) {
            float  pk = P[d][k];
            float4 pv = *(const float4*)&P[k][q];
            acc.x += pk * pv.x; acc.y += pk * pv.y;
            acc.z += pk * pv.z; acc.w += pk * pv.w;
        }
        *(float4*)&P2[d][q] = acc;
    }
    __syncthreads();

    // ---- dense gather: thread owns u32 column tid (2 bf16 cols) ----
    const u32* yr = (const u32*)(Y + (size_t)nb * DIM) + tid;
    u32*       xo = (u32*)(xg + (size_t)nb * DIM) + tid;
    float2 bgv = *(const float2*)&bg[2 * tid];

    // preload + unpack all 40 source-row values (static indexing -> registers)
    float v0[NPS], v1[NPS];
#pragma unroll
    for (int s = 0; s < NPS; s++) {
        u32 r = yr[(size_t)s * (DIM / 2)];
        v0[s] = bf2f(r & 0xffffu);
        v1[s] = bf2f(r >> 16);
    }

#pragma unroll 4
    for (int d = 0; d < NPS; d++) {
        float a0 = bgv.x, a1 = bgv.y;
#pragma unroll
        for (int sq = 0; sq < NPS; sq += 4) {
            float4 p = *(const float4*)&P2[d][sq];
            a0 += p.x * v0[sq] + p.y * v0[sq + 1] + p.z * v0[sq + 2] + p.w * v0[sq + 3];
            a1 += p.x * v1[sq] + p.y * v1[sq + 1] + p.z * v1[sq + 2] + p.w * v1[sq + 3];
        }
        xo[(size_t)d * (DIM / 2)] = pack2(a0, a1);
    }
}

// ---------- A2 = xg @ W2  [N,64] bf16, dense streaming MFMA, no LDS ----------
extern "C" __global__ __launch_bounds__(256)
void k_a2(const u16* __restrict__ xg, const u16* __restrict__ W2T,
          u16* __restrict__ A2) {
    int tid = threadIdx.x, lane = tid & 63, w = tid >> 6;
    int m0  = blockIdx.x * 256 + w * 64;
    int fr  = lane & 15, kq = (lane >> 4) * 8;
    f32x4 acc[4][4] = {};

    for (int kt = 0; kt < 16; kt++) {
        bf16x8 bv[4];
#pragma unroll
        for (int fn = 0; fn < 4; fn++)
            bv[fn] = *(const bf16x8*)&W2T[(size_t)(fn * 16 + fr) * DIM + kt * 32 + kq];
#pragma unroll
        for (int fm = 0; fm < 4; fm++) {
            bf16x8 av = *(const bf16x8*)&xg[(size_t)(m0 + fm * 16 + fr) * DIM + kt * 32 + kq];
#pragma unroll
            for (int fn = 0; fn < 4; fn++)
                acc[fm][fn] = __builtin_amdgcn_mfma_f32_16x16x32_bf16(
                    av, bv[fn], acc[fm][fn], 0, 0, 0);
        }
    }
#pragma unroll
    for (int fm = 0; fm < 4; fm++) {
        int mb = m0 + fm * 16 + (lane >> 4) * 4;
#pragma unroll
        for (int fn = 0; fn < 4; fn++) {
            int col = fn * 16 + fr;
#pragma unroll
            for (int r = 0; r < 4; r++)
                A2[(size_t)(mb + r) * HID + col] = f2bf(acc[fm][fn][r]);
        }
    }
}

// ---------- q1[b] = v_n[b] @ W1 + b1 + b2  [B,64] fp32 ----------
extern "C" __global__ __launch_bounds__(256)
void k_q1(const u16* __restrict__ xg, const u16* __restrict__ W1T,
          const float* __restrict__ b1, const float* __restrict__ b2,
          const int* __restrict__ sidx, float* __restrict__ q1g) {
    __shared__ __align__(16) u16 vs[64 * 520];
    int tid = threadIdx.x, lane = tid & 63, w = tid >> 6;
    int b0  = blockIdx.x * 64;

    for (int t = w; t < 64; t += 4) {
        int brow = b0 + t;
        size_t node = (size_t)brow * NPS + sidx[brow * SPS + SPS - 1];
        GLOAD_LDS16(xg + node * DIM + lane * 8, vs + t * 520);
    }
    __syncthreads();

    int fr = lane & 15, kq = (lane >> 4) * 8;
    f32x4 acc[4] = {};
    for (int kt = 0; kt < 16; kt++) {
        bf16x8 av = *(const bf16x8*)&vs[(w * 16 + fr) * 520 + kt * 32 + kq];
#pragma unroll
        for (int fn = 0; fn < 4; fn++) {
            bf16x8 bv = *(const bf16x8*)&W1T[(size_t)(fn * 16 + fr) * DIM + kt * 32 + kq];
            acc[fn] = __builtin_amdgcn_mfma_f32_16x16x32_bf16(av, bv, acc[fn], 0, 0, 0);
        }
    }
#pragma unroll
    for (int fn = 0; fn < 4; fn++) {
        int col = fn * 16 + fr;
        float bb = b1[col] + b2[col];
#pragma unroll
        for (int r = 0; r < 4; r++) {
            int brow = b0 + w * 16 + (lane >> 4) * 4 + r;
            q1g[(size_t)brow * HID + col] = acc[fn][r] + bb;
        }
    }
}

// ---------- lite attention pooling, one block per session (no big LDS) ----------
extern "C" __global__ __launch_bounds__(256)
void k_attn(const u16* __restrict__ xg, const u16* __restrict__ A2,
            const float* __restrict__ q1g, const float* __restrict__ Wq,
            const float* __restrict__ bq, const u16* __restrict__ W3T,
            const float* __restrict__ b3, const int* __restrict__ sidx,
            float* __restrict__ out) {
    __shared__ __align__(16) u16 a2s[SPS * HID];   // 6.4 KB
    __shared__ float q1s[64], wqs[64], alphas[64], sgs[512], part[256];
    __shared__ int   nodes[64];
    int tid = threadIdx.x, lane = tid & 63, w = tid >> 6;
    int b = blockIdx.x, sb = b * SPS;
    int nb = b * NPS;

    if (tid < SPS) nodes[tid] = nb + sidx[sb + tid];
    if (tid < 64) { q1s[tid] = q1g[(size_t)b * HID + tid]; wqs[tid] = Wq[tid]; }
    __syncthreads();

    // stage a2 token rows: 50 x 64 bf16 = 1600 u32
    {
        const u32* A2u = (const u32*)A2;
        u32* a2u = (u32*)a2s;
        for (int i = tid; i < SPS * (HID / 2); i += 256) {
            int r = i >> 5, c = i & 31;
            a2u[i] = A2u[(size_t)nodes[r] * (HID / 2) + c];
        }
    }
    __syncthreads();

    // alphas: wave w handles tokens w, w+4, ...
    float bqf = bq[0];
    for (int t = w; t < SPS; t += 4) {
        float x = bf2f(a2s[t * HID + lane]) + q1s[lane];
        float sg = 1.0f / (1.0f + __expf(-x));
        float s = sg * wqs[lane];
        s += __shfl_xor(s, 1);  s += __shfl_xor(s, 2);  s += __shfl_xor(s, 4);
        s += __shfl_xor(s, 8);  s += __shfl_xor(s, 16); s += __shfl_xor(s, 32);
        if (lane == 0) alphas[t] = s + bqf;
    }
    __syncthreads();

    // s_g: thread owns u32 column tid (2 bf16 cols); gather rows from xg (L3-hot)
    {
        const u32* xgu = (const u32*)xg;
        float a0 = 0.f, a1 = 0.f;
#pragma unroll 10
        for (int t = 0; t < SPS; t++) {
            float al = alphas[t];
            u32 xv = xgu[(size_t)nodes[t] * (DIM / 2) + tid];
            a0 += al * bf2f(xv & 0xffffu);
            a1 += al * bf2f(xv >> 16);
        }
        sgs[2 * tid] = a0; sgs[2 * tid + 1] = a1;
    }
    __syncthreads();

    // h_s = [v_n, s_g] @ W3 + b3  (W3T bf16 [64][1024]); wave w covers k 256w..+256
    {
        float s = 0.f;
        const u16* wp = W3T + (size_t)lane * 1024 + 256 * w;
        if (w < 2) {
            const u16* vp = xg + (size_t)nodes[SPS - 1] * DIM + 256 * w;
            for (int kk = 0; kk < 256; kk += 8) {
                uint4 vv = *(const uint4*)(vp + kk);
                uint4 ww = *(const uint4*)(wp + kk);
                s += bf2f(vv.x & 0xffffu) * bf2f(ww.x & 0xffffu)
                   + bf2f(vv.x >> 16)     * bf2f(ww.x >> 16)
                   + bf2f(vv.y & 0xffffu) * bf2f(ww.y & 0xffffu)
                   + bf2f(vv.y >> 16)     * bf2f(ww.y >> 16)
                   + bf2f(vv.z & 0xffffu) * bf2f(ww.z & 0xffffu)
                   + bf2f(vv.z >> 16)     * bf2f(ww.z >> 16)
                   + bf2f(vv.w & 0xffffu) * bf2f(ww.w & 0xffffu)
                   + bf2f(vv.w >> 16)     * bf2f(ww.w >> 16);
            }
        } else {
            const float* sp = sgs + 256 * (w - 2);
            for (int kk = 0; kk < 256; kk += 8) {
                uint4 ww = *(const uint4*)(wp + kk);
                s += sp[kk + 0] * bf2f(ww.x & 0xffffu) + sp[kk + 1] * bf2f(ww.x >> 16)
                   + sp[kk + 2] * bf2f(ww.y & 0xffffu) + sp[kk + 3] * bf2f(ww.y >> 16)
                   + sp[kk + 4] * bf2f(ww.z & 0xffffu) + sp[kk + 5] * bf2f(ww.z >> 16)
                   + sp[kk + 6] * bf2f(ww.w & 0xffffu) + sp[kk + 7] * bf2f(ww.w >> 16);
            }
        }
        part[w * 64 + lane] = s;
    }
    __syncthreads();
    if (tid < 64) {
        out[b * HID + tid] = part[tid] + part[64 + tid] + part[128 + tid]
                           + part[192 + tid] + b3[tid];
    }
}

extern "C" void kernel_launch(void* const* d_in, const int* in_sizes, int n_in,
                              void* d_out, int out_size, void* d_ws, size_t ws_size,
                              hipStream_t stream) {
    const float* hidden = (const float*)d_in[0];
    const float* Wg     = (const float*)d_in[1];
    const float* bg     = (const float*)d_in[2];
    const float* W1     = (const float*)d_in[3];
    const float* b1     = (const float*)d_in[4];
    const float* W2     = (const float*)d_in[5];
    const float* b2     = (const float*)d_in[6];
    const float* Wq     = (const float*)d_in[7];
    const float* bq     = (const float*)d_in[8];
    const float* W3     = (const float*)d_in[9];
    const float* b3     = (const float*)d_in[10];
    const int*   eidx   = (const int*)d_in[11];
    const int*   sidx   = (const int*)d_in[13];
    int Etot = in_sizes[11] / 2;

    char* ws = (char*)d_ws;
    // region A [0,160MB): xg (written by k_prop, read by a2/q1/attn)
    u16* xg  = (u16*)ws;
    // region B [160,320MB): Y (k_gemm -> k_prop), then A2/q1g after Y is dead
    u16* Y   = (u16*)(ws + (size_t)NNODES * DIM * 2);
    u16* WgT = (u16*)(ws + (size_t)NNODES * DIM * 4);      // 512x512 bf16
    u16* W2T = WgT + DIM * DIM;                            // 64x512  bf16
    u16* W1T = W2T + DIM * HID;                            // 64x512  bf16
    u16* W3T = W1T + DIM * HID;                            // 64x1024 bf16
    u16*   A2  = Y;                                        // N*64 bf16 (20 MB)
    float* q1g = (float*)((char*)Y + (size_t)NNODES * HID * 2);  // B*64 fp32

    k_convT<<<dim3((DIM * DIM + 255) / 256), 256, 0, stream>>>(Wg, WgT, DIM, DIM);
    k_convT<<<dim3((DIM * HID + 255) / 256), 256, 0, stream>>>(W2, W2T, DIM, HID);
    k_convT<<<dim3((DIM * HID + 255) / 256), 256, 0, stream>>>(W1, W1T, DIM, HID);
    k_convT<<<dim3((2 * DIM * HID + 255) / 256), 256, 0, stream>>>(W3, W3T, 2 * DIM, HID);
    k_gemm<<<dim3(GEMM_NBLK), 256, 0, stream>>>(hidden, WgT, Y);
    k_prop<<<dim3(B_SESS), 256, 0, stream>>>(Y, eidx, Etot, bg, xg);
    k_a2<<<dim3(NNODES / 256), 256, 0, stream>>>(xg, W2T, A2);
    k_q1<<<dim3(B_SESS / 64), 256, 0, stream>>>(xg, W1T, b1, b2, sidx, q1g);
    k_attn<<<dim3(B_SESS), 256, 0, stream>>>(xg, A2, q1g, Wq, bq, W3T, b3,
                                             sidx, (float*)d_out);
}